// Round 11
// baseline (30.744 us; speedup 1.0000x reference)
//
#include <hip/hip_runtime.h>
#include <hip/hip_bf16.h>

constexpr int N_PTS  = 5000;
constexpr int CF     = 32;
constexpr int K_NMS  = 64;
constexpr int SEGS   = 32;                      // candidate segments (R7-best)
constexpr int SEGLEN = 157;                     // ceil(5000/32); seg 31 has 133
constexpr int XBU    = 79;                      // point chunks of 64 (79*64 = 5056)
#define R2 0.01f

// ---------------- Node 1: score + epilogue (fused) ---------------------------
// GEMV/normalize arithmetic UNCHANGED since round 1 — bit-matches numpy
// (absmax 0.0 every round). Writes the un-suppressed score default to out;
// node 2 conditionally overwrites suppressed entries with s*1e-4.
__global__ __launch_bounds__(64) void score_feat_kernel(
    const float* __restrict__ xyz,       // [N,3]
    const float* __restrict__ feats,     // [C,N]
    const float* __restrict__ W1,        // [C,C]
    const float* __restrict__ b1,        // [C]
    const float* __restrict__ bn_gamma,  // [C]
    const float* __restrict__ bn_beta,   // [C]
    const float* __restrict__ bn_mean,   // [C]
    const float* __restrict__ bn_var,    // [C]
    const float* __restrict__ W2,        // [1,C]
    const float* __restrict__ b2,        // [1]
    float* __restrict__ out,             // [3N + N + N*C]
    float* __restrict__ scores_ws,       // [N] raw scores (fallback path)
    float4* __restrict__ pcd4)           // [N] {x,y,z,score}
{
    __shared__ float sW1[CF * CF];
    __shared__ float sScale[CF], sB1[CF], sMean[CF], sBeta[CF], sW2[CF];
    __shared__ float sB2;
    __shared__ float sFeat[64][33];
    __shared__ float sXyz[192];
    const int t = threadIdx.x;
    for (int k = t; k < CF * CF; k += 64) sW1[k] = W1[k];
    if (t < CF) {
        sScale[t] = bn_gamma[t] / sqrtf(bn_var[t] + 1e-5f);
        sB1[t]    = b1[t];
        sMean[t]  = bn_mean[t];
        sBeta[t]  = bn_beta[t];
        sW2[t]    = W2[t];
    }
    if (t == 0) sB2 = b2[0];
    __syncthreads();

    const int pb = blockIdx.x * 64;
    const int i  = pb + t;
    const int nvalid = min(64, N_PTS - pb);

    if (i < N_PTS) {
        float f[CF];
        #pragma unroll
        for (int c = 0; c < CF; ++c) f[c] = feats[c * N_PTS + i];

        // ---- score head (verbatim arithmetic)
        float h2 = 0.f;
        #pragma unroll
        for (int c = 0; c < CF; ++c) {
            float acc = 0.f;
            #pragma unroll
            for (int k = 0; k < CF; ++k) acc = fmaf(sW1[c * CF + k], f[k], acc);
            float h1 = acc + sB1[c];
            float hb = (h1 - sMean[c]) * sScale[c] + sBeta[c];
            hb = fmaxf(hb, 0.f);
            h2 = fmaf(sW2[c], hb, h2);
        }
        const float xlin = h2 + sB2;
        const float s = 1.f / (1.f + expf(-xlin));
        scores_ws[i] = s;
        out[3 * N_PTS + i] = s;              // default: not suppressed

        const float x0 = xyz[3 * i + 0];
        const float x1 = xyz[3 * i + 1];
        const float x2 = xyz[3 * i + 2];
        pcd4[i] = make_float4(x0, x1, x2, s);
        sXyz[3 * t + 0] = x0;
        sXyz[3 * t + 1] = x1;
        sXyz[3 * t + 2] = x2;

        // ---- L2-normalize (verbatim arithmetic), reuse f[]
        float ssum = 0.f;
        #pragma unroll
        for (int c = 0; c < CF; ++c) ssum = fmaf(f[c], f[c], ssum);
        const float inv = 1.f / fmaxf(sqrtf(ssum), 1e-12f);
        #pragma unroll
        for (int c = 0; c < CF; ++c) sFeat[t][c] = f[c] * inv;
    }
    __syncthreads();

    // ---- coalesced slab stores (feats then xyz)
    #pragma unroll 8
    for (int k = 0; k < 32; ++k) {
        const int idx = k * 64 + t;
        if (idx < nvalid * CF)
            out[4 * N_PTS + pb * CF + idx] = sFeat[idx >> 5][idx & 31];
    }
    #pragma unroll
    for (int k = 0; k < 3; ++k) {
        const int idx = k * 64 + t;
        if (idx < nvalid * 3)
            out[3 * pb + idx] = sXyz[idx];
    }
}

// ---------------- Node 2: seg scan + idempotent suppression ------------------
// R7's measured-best scan structure (uniform-load broadcast, unroll 8).
// Suppression is an existence test (valid while ball-count <= 64: self is
// always in the first-64 window, so max==s  <=>  no in-ball score > s).
// Any wave finding a greater in-ball neighbor stores the SAME value
// s*1e-4 -> order-free, race-free by idempotence. No ws2, no combine node.
__global__ __launch_bounds__(256) void nms_suppress_kernel(
    const float4* __restrict__ pcd4,    // [N] {x,y,z,score}
    float* __restrict__ out_scores)     // out + 3N (pre-filled with s)
{
    const int lane = threadIdx.x & 63;
    const int wave = threadIdx.x >> 6;
    const int seg  = __builtin_amdgcn_readfirstlane(blockIdx.y * 4 + wave);
    const int j0   = seg * SEGLEN;
    const int jn   = min(SEGLEN, N_PTS - j0);    // 157 (133 for seg 31)
    const int p    = blockIdx.x * 64 + lane;

    float px, py, pz, ps;
    if (p < N_PTS) {
        const float4 q = pcd4[p];
        px = q.x; py = q.y; pz = q.z; ps = q.w;
    } else {
        px = 1e18f; py = 0.f; pz = 0.f; ps = 1e30f;  // never suppressed
    }

    bool flag = false;
    #pragma unroll 8
    for (int jj = 0; jj < jn; ++jj) {
        const float4 c = pcd4[j0 + jj];          // wave-uniform address
        // exact numpy order: ((dx*dx + dy*dy) + dz*dz), no FMA contraction
        const float dx = __fsub_rn(px, c.x);
        const float dy = __fsub_rn(py, c.y);
        const float dz = __fsub_rn(pz, c.z);
        const float d2 = __fadd_rn(__fadd_rn(__fmul_rn(dx, dx),
                                             __fmul_rn(dy, dy)),
                                   __fmul_rn(dz, dz));
        flag = flag | ((d2 < R2) & (c.w > ps)); // strict >: ties not suppressed
    }
    if (p < N_PTS && flag)
        out_scores[p] = ps * 1e-4f;              // idempotent constant store
}

// ---------------- Fallback (small ws): wave-per-point NMS (round-1, exact) ---
__global__ __launch_bounds__(256) void nms_kernel(
    const float* __restrict__ xyz,
    const float* __restrict__ scores,
    float* __restrict__ out_scores)
{
    __shared__ float sxyz[N_PTS * 3];
    __shared__ float sscr[N_PTS];
    const int t = threadIdx.x;
    for (int k = t; k < N_PTS * 3; k += 256) sxyz[k] = xyz[k];
    for (int k = t; k < N_PTS; k += 256) sscr[k] = scores[k];
    __syncthreads();

    const int wave = t >> 6;
    const int lane = t & 63;
    const unsigned long long lt_mask = (lane == 0) ? 0ull : (~0ull >> (64 - lane));

    for (int p = blockIdx.x * 4 + wave; p < N_PTS; p += 256 * 4) {
        const float px = sxyz[3*p], py = sxyz[3*p+1], pz = sxyz[3*p+2];
        int cnt = 0;
        float m = 0.f;
        for (int base = 0; base < N_PTS; base += 64) {
            const int j = base + lane;
            bool inball = false;
            if (j < N_PTS) {
                const float dx = __fsub_rn(px, sxyz[3*j+0]);
                const float dy = __fsub_rn(py, sxyz[3*j+1]);
                const float dz = __fsub_rn(pz, sxyz[3*j+2]);
                const float d2 = __fadd_rn(__fadd_rn(__fmul_rn(dx, dx),
                                                     __fmul_rn(dy, dy)),
                                           __fmul_rn(dz, dz));
                inball = d2 < R2;
            }
            const unsigned long long mask = __ballot(inball);
            const int prefix = __popcll(mask & lt_mask);
            if (inball && (cnt + prefix) < K_NMS) m = fmaxf(m, sscr[j]);
            cnt += __popcll(mask);
            if (cnt >= K_NMS) break;
        }
        #pragma unroll
        for (int off = 32; off >= 1; off >>= 1)
            m = fmaxf(m, __shfl_xor(m, off, 64));
        if (lane == 0) {
            const float s = sscr[p];
            out_scores[p] = (m == s) ? s : s * 1e-4f;
        }
    }
}

extern "C" void kernel_launch(void* const* d_in, const int* in_sizes, int n_in,
                              void* d_out, int out_size, void* d_ws, size_t ws_size,
                              hipStream_t stream) {
    const float* xyz      = (const float*)d_in[0];
    const float* feats    = (const float*)d_in[1];
    const float* W1       = (const float*)d_in[2];
    const float* b1       = (const float*)d_in[3];
    const float* bn_gamma = (const float*)d_in[4];
    const float* bn_beta  = (const float*)d_in[5];
    const float* bn_mean  = (const float*)d_in[6];
    const float* bn_var   = (const float*)d_in[7];
    const float* W2       = (const float*)d_in[8];
    const float* b2       = (const float*)d_in[9];
    float* out = (float*)d_out;

    char* wsb = (char*)d_ws;
    float*  scores_ws = (float*)wsb;                                  // [N]
    float4* pcd4      = (float4*)(wsb + 20096);                       // [N] (16B-aligned)
    const size_t need = 20096 + N_PTS * sizeof(float4);

    score_feat_kernel<<<XBU, 64, 0, stream>>>(
        xyz, feats, W1, b1, bn_gamma, bn_beta, bn_mean, bn_var, W2, b2,
        out, scores_ws, pcd4);

    if (ws_size >= need) {
        dim3 g(XBU, SEGS / 4);                                        // (79,8)
        nms_suppress_kernel<<<g, 256, 0, stream>>>(pcd4, out + 3 * N_PTS);
    } else {
        nms_kernel<<<256, 256, 0, stream>>>(xyz, scores_ws, out + 3 * N_PTS);
    }
}

// Round 12
// 26.364 us; speedup vs baseline: 1.1661x; 1.1661x over previous
//
#include <hip/hip_runtime.h>
#include <hip/hip_bf16.h>

constexpr int N_PTS  = 5000;
constexpr int CF     = 32;
constexpr int K_NMS  = 64;
constexpr int SEGS   = 32;                      // candidate segments
constexpr int SEGLEN = 157;                     // ceil(5000/32); seg 31 has 133
constexpr int XBU    = 79;                      // point chunks of 64 (79*64 = 5056)
#define R2 0.01f

// ---------------- Kernel 1: score header only (GEMV+BN+ReLU+GEMV+sigmoid) ----
// Arithmetic UNCHANGED since round 1 — bit-matches numpy reference (absmax 0.0).
// 79 blocks x 64 threads: one point per thread, 79 CUs for load parallelism.
__global__ __launch_bounds__(64) void score_kernel(
    const float* __restrict__ xyz,       // [N,3]
    const float* __restrict__ feats,     // [C,N]
    const float* __restrict__ W1,        // [C,C]
    const float* __restrict__ b1,        // [C]
    const float* __restrict__ bn_gamma,  // [C]
    const float* __restrict__ bn_beta,   // [C]
    const float* __restrict__ bn_mean,   // [C]
    const float* __restrict__ bn_var,    // [C]
    const float* __restrict__ W2,        // [1,C]
    const float* __restrict__ b2,        // [1]
    float* __restrict__ scores_ws,       // [N] raw sigmoid scores
    float4* __restrict__ pcd4)           // [N] {x,y,z,score}
{
    __shared__ float sW1[CF * CF];
    __shared__ float sScale[CF], sB1[CF], sMean[CF], sBeta[CF], sW2[CF];
    __shared__ float sB2;
    const int t = threadIdx.x;
    for (int k = t; k < CF * CF; k += 64) sW1[k] = W1[k];
    if (t < CF) {
        sScale[t] = bn_gamma[t] / sqrtf(bn_var[t] + 1e-5f);
        sB1[t]    = b1[t];
        sMean[t]  = bn_mean[t];
        sBeta[t]  = bn_beta[t];
        sW2[t]    = W2[t];
    }
    if (t == 0) sB2 = b2[0];
    __syncthreads();

    const int i = blockIdx.x * 64 + t;
    if (i >= N_PTS) return;

    float f[CF];
    #pragma unroll
    for (int c = 0; c < CF; ++c) f[c] = feats[c * N_PTS + i];

    float h2 = 0.f;
    #pragma unroll
    for (int c = 0; c < CF; ++c) {
        float acc = 0.f;
        #pragma unroll
        for (int k = 0; k < CF; ++k) acc = fmaf(sW1[c * CF + k], f[k], acc);
        float h1 = acc + sB1[c];
        float hb = (h1 - sMean[c]) * sScale[c] + sBeta[c];
        hb = fmaxf(hb, 0.f);
        h2 = fmaf(sW2[c], hb, h2);
    }
    const float xlin = h2 + sB2;
    const float s = 1.f / (1.f + expf(-xlin));
    scores_ws[i] = s;
    pcd4[i] = make_float4(xyz[3 * i + 0], xyz[3 * i + 1], xyz[3 * i + 2], s);
}

// ---------------- NMS phase 1: uniform-load seg scan (UNCHANGED from R6) -----
__global__ __launch_bounds__(256) void nms_seg_u_kernel(
    const float4* __restrict__ pcd4,    // [N] {x,y,z,score}
    uint2* __restrict__ ws2)            // [SEGS][N] (cnt, max-bits)
{
    const int lane = threadIdx.x & 63;
    const int wave = threadIdx.x >> 6;
    const int seg  = __builtin_amdgcn_readfirstlane(blockIdx.y * 4 + wave);
    const int j0   = seg * SEGLEN;
    const int jn   = min(SEGLEN, N_PTS - j0);    // 157 (133 for seg 31)
    const int p    = blockIdx.x * 64 + lane;

    float px, py, pz;
    if (p < N_PTS) {
        const float4 q = pcd4[p];
        px = q.x; py = q.y; pz = q.z;
    } else {
        px = 1e18f; py = 0.f; pz = 0.f;
    }

    int cnt = 0;
    float m = 0.f;
    #pragma unroll 8
    for (int jj = 0; jj < jn; ++jj) {
        const float4 c = pcd4[j0 + jj];          // wave-uniform address
        // exact numpy order: ((dx*dx + dy*dy) + dz*dz), no FMA contraction
        const float dx = __fsub_rn(px, c.x);
        const float dy = __fsub_rn(py, c.y);
        const float dz = __fsub_rn(pz, c.z);
        const float d2 = __fadd_rn(__fadd_rn(__fmul_rn(dx, dx),
                                             __fmul_rn(dy, dy)),
                                   __fmul_rn(dz, dz));
        const bool in = d2 < R2;
        cnt += in ? 1 : 0;
        m = fmaxf(m, in ? c.w : 0.0f);           // scores > 0, m init 0
    }
    if (p < N_PTS)
        ws2[seg * N_PTS + p] = make_uint2((unsigned)cnt, __float_as_uint(m));
}

// ---------------- NMS phase 2 + epilogue: combine, suppress, normalize, xyz --
// 79 blocks x 64 threads, one point per thread. Also carries the (NMS-
// independent) feature L2-normalize + xyz passthrough — verbatim arithmetic.
__global__ __launch_bounds__(64) void combine_epilogue_kernel(
    const float* __restrict__ xyz,
    const float* __restrict__ feats,     // [C,N]
    const float* __restrict__ scores,
    const uint2* __restrict__ ws2,
    float* __restrict__ out)             // [3N + N + N*C]
{
    const int p = blockIdx.x * 64 + threadIdx.x;
    if (p >= N_PTS) return;

    // ---- combine 32 segment partials
    int total = 0;
    float m = 0.f;
    #pragma unroll
    for (int s = 0; s < SEGS; ++s) {
        const uint2 v = ws2[s * N_PTS + p];
        total += (int)v.x;
        m = fmaxf(m, __uint_as_float(v.y));
    }
    if (total > K_NMS) {
        // exact first-64-in-index-order re-scan (essentially never taken)
        const float px = xyz[3*p], py = xyz[3*p+1], pz = xyz[3*p+2];
        m = 0.f;
        int taken = 0;
        for (int j = 0; j < N_PTS && taken < K_NMS; ++j) {
            const float dx = __fsub_rn(px, xyz[3*j+0]);
            const float dy = __fsub_rn(py, xyz[3*j+1]);
            const float dz = __fsub_rn(pz, xyz[3*j+2]);
            const float d2 = __fadd_rn(__fadd_rn(__fmul_rn(dx, dx),
                                                 __fmul_rn(dy, dy)),
                                       __fmul_rn(dz, dz));
            if (d2 < R2) { m = fmaxf(m, scores[j]); ++taken; }
        }
    }
    const float sc = scores[p];
    out[3 * N_PTS + p] = (m == sc) ? sc : sc * 1e-4f;

    // ---- xyz passthrough
    out[3 * p + 0] = xyz[3 * p + 0];
    out[3 * p + 1] = xyz[3 * p + 1];
    out[3 * p + 2] = xyz[3 * p + 2];

    // ---- L2-normalized features (verbatim arithmetic from round 1)
    float f[CF];
    #pragma unroll
    for (int c = 0; c < CF; ++c) f[c] = feats[c * N_PTS + p];
    float ssum = 0.f;
    #pragma unroll
    for (int c = 0; c < CF; ++c) ssum = fmaf(f[c], f[c], ssum);
    const float inv = 1.f / fmaxf(sqrtf(ssum), 1e-12f);
    float* fo = out + 4 * N_PTS + p * CF;
    #pragma unroll
    for (int c = 0; c < CF; ++c) fo[c] = f[c] * inv;
}

// ---------------- Fallback (small ws): wave-per-point NMS (round-1, exact) ---
// (writes scores only; epilogue handled by combine path normally — this
// fallback keeps the full original structure for tiny-ws safety)
__global__ __launch_bounds__(256) void nms_kernel(
    const float* __restrict__ xyz,
    const float* __restrict__ scores,
    float* __restrict__ out_scores)
{
    __shared__ float sxyz[N_PTS * 3];
    __shared__ float sscr[N_PTS];
    const int t = threadIdx.x;
    for (int k = t; k < N_PTS * 3; k += 256) sxyz[k] = xyz[k];
    for (int k = t; k < N_PTS; k += 256) sscr[k] = scores[k];
    __syncthreads();

    const int wave = t >> 6;
    const int lane = t & 63;
    const unsigned long long lt_mask = (lane == 0) ? 0ull : (~0ull >> (64 - lane));

    for (int p = blockIdx.x * 4 + wave; p < N_PTS; p += 256 * 4) {
        const float px = sxyz[3*p], py = sxyz[3*p+1], pz = sxyz[3*p+2];
        int cnt = 0;
        float m = 0.f;
        for (int base = 0; base < N_PTS; base += 64) {
            const int j = base + lane;
            bool inball = false;
            if (j < N_PTS) {
                const float dx = __fsub_rn(px, sxyz[3*j+0]);
                const float dy = __fsub_rn(py, sxyz[3*j+1]);
                const float dz = __fsub_rn(pz, sxyz[3*j+2]);
                const float d2 = __fadd_rn(__fadd_rn(__fmul_rn(dx, dx),
                                                     __fmul_rn(dy, dy)),
                                           __fmul_rn(dz, dz));
                inball = d2 < R2;
            }
            const unsigned long long mask = __ballot(inball);
            const int prefix = __popcll(mask & lt_mask);
            if (inball && (cnt + prefix) < K_NMS) m = fmaxf(m, sscr[j]);
            cnt += __popcll(mask);
            if (cnt >= K_NMS) break;
        }
        #pragma unroll
        for (int off = 32; off >= 1; off >>= 1)
            m = fmaxf(m, __shfl_xor(m, off, 64));
        if (lane == 0) {
            const float s = sscr[p];
            out_scores[p] = (m == s) ? s : s * 1e-4f;
        }
    }
}

// epilogue-only kernel for the fallback path (xyz + normalized feats)
__global__ __launch_bounds__(64) void epilogue_kernel(
    const float* __restrict__ xyz,
    const float* __restrict__ feats,
    float* __restrict__ out)
{
    const int p = blockIdx.x * 64 + threadIdx.x;
    if (p >= N_PTS) return;
    out[3 * p + 0] = xyz[3 * p + 0];
    out[3 * p + 1] = xyz[3 * p + 1];
    out[3 * p + 2] = xyz[3 * p + 2];
    float f[CF];
    #pragma unroll
    for (int c = 0; c < CF; ++c) f[c] = feats[c * N_PTS + p];
    float ssum = 0.f;
    #pragma unroll
    for (int c = 0; c < CF; ++c) ssum = fmaf(f[c], f[c], ssum);
    const float inv = 1.f / fmaxf(sqrtf(ssum), 1e-12f);
    float* fo = out + 4 * N_PTS + p * CF;
    #pragma unroll
    for (int c = 0; c < CF; ++c) fo[c] = f[c] * inv;
}

extern "C" void kernel_launch(void* const* d_in, const int* in_sizes, int n_in,
                              void* d_out, int out_size, void* d_ws, size_t ws_size,
                              hipStream_t stream) {
    const float* xyz      = (const float*)d_in[0];
    const float* feats    = (const float*)d_in[1];
    const float* W1       = (const float*)d_in[2];
    const float* b1       = (const float*)d_in[3];
    const float* bn_gamma = (const float*)d_in[4];
    const float* bn_beta  = (const float*)d_in[5];
    const float* bn_mean  = (const float*)d_in[6];
    const float* bn_var   = (const float*)d_in[7];
    const float* W2       = (const float*)d_in[8];
    const float* b2       = (const float*)d_in[9];
    float* out = (float*)d_out;

    char* wsb = (char*)d_ws;
    float*  scores_ws = (float*)wsb;                                  // [N]
    float4* pcd4      = (float4*)(wsb + 20096);                       // [N] (16B-aligned)
    uint2*  ws2       = (uint2*)(wsb + 20096 + N_PTS * sizeof(float4)); // [SEGS][N]
    const size_t need = 20096 + N_PTS * sizeof(float4)
                      + (size_t)SEGS * N_PTS * sizeof(uint2);

    score_kernel<<<XBU, 64, 0, stream>>>(
        xyz, feats, W1, b1, bn_gamma, bn_beta, bn_mean, bn_var, W2, b2,
        scores_ws, pcd4);

    if (ws_size >= need) {
        dim3 g(XBU, 8);                                               // 632 blocks
        nms_seg_u_kernel<<<g, 256, 0, stream>>>(pcd4, ws2);
        combine_epilogue_kernel<<<XBU, 64, 0, stream>>>(
            xyz, feats, scores_ws, ws2, out);
    } else {
        nms_kernel<<<256, 256, 0, stream>>>(xyz, scores_ws, out + 3 * N_PTS);
        epilogue_kernel<<<XBU, 64, 0, stream>>>(xyz, feats, out);
    }
}